// Round 10
// baseline (165.782 us; speedup 1.0000x reference)
//
#include <hip/hip_runtime.h>

#define NN 10000
#define NE 640000
#define NB 313          // buckets of 32 nodes; also # partition blocks
#define RSTRIDE 2688    // slots per bucket (mean 2045, sigma~45)
#define EPB 2048        // edges per partition block
#define G1B 1250        // gemm1 blocks (8 rows each)

__device__ __forceinline__ unsigned short f2bf(float x) {   // RNE
    unsigned u = __float_as_uint(x);
    u += 0x7FFFu + ((u >> 16) & 1u);
    return (unsigned short)(u >> 16);
}
__device__ __forceinline__ float bflo(unsigned u) { return __uint_as_float(u << 16); }
__device__ __forceinline__ float bfhi(unsigned u) { return __uint_as_float(u & 0xFFFF0000u); }
__device__ __forceinline__ float bf1(unsigned short h) { return __uint_as_float((unsigned)h << 16); }

struct SMpart { int hist[NB]; int scanv[NB + 1]; int gbase[NB]; int lcur[NB];
                unsigned stage[EPB]; };
struct SMbuild { int sbase[NB + 1]; int hist32[32]; int cur32[32];
                 unsigned stage[RSTRIDE]; };
union SMu {
    SMpart p;
    SMbuild b;
    float xs[8][128];
};

__global__ void zero_kernel(int* __restrict__ cur) {
    if (threadIdx.x < NB) cur[threadIdx.x] = 0;
}

// ---- gemm1: 8 rows of Y = X[f32] @ W[128x128] -> bf16 ----
__device__ __forceinline__ void gemm1_block(const float* __restrict__ X,
                                            const float* __restrict__ W,
                                            unsigned short* __restrict__ Y,
                                            float (*xs)[128], int vb, int tid) {
    int row0 = vb * 8;
    for (int idx = tid; idx < 8 * 128; idx += 256) {
        int r = idx >> 7, k = idx & 127;
        xs[r][k] = X[(size_t)(row0 + r) * 128 + k];
    }
    __syncthreads();
    int ct = tid & 31, r = tid >> 5, c = ct * 4;
    float4 acc = make_float4(0.f, 0.f, 0.f, 0.f);
    #pragma unroll 8
    for (int k = 0; k < 128; ++k) {
        float xv = xs[r][k];
        float4 w = *reinterpret_cast<const float4*>(W + (size_t)k * 128 + c);
        acc.x += xv * w.x; acc.y += xv * w.y; acc.z += xv * w.z; acc.w += xv * w.w;
    }
    ushort4 o;
    o.x = f2bf(acc.x); o.y = f2bf(acc.y); o.z = f2bf(acc.z); o.w = f2bf(acc.w);
    *reinterpret_cast<ushort4*>(Y + (size_t)(row0 + r) * 128 + c) = o;
}

// ---- partition: one block of EPB edges -> bucketed records ----
__device__ __forceinline__ void partition_block(const int* __restrict__ src,
                                                const int* __restrict__ dst,
                                                int* __restrict__ bcur,
                                                unsigned* __restrict__ edge_part,
                                                SMpart& p, int bid, int tid) {
    for (int i = tid; i < NB; i += 256) p.hist[i] = 0;
    __syncthreads();
    int gi = bid * EPB + tid * 8;
    unsigned rec[8];
    bool act = gi < NE;
    if (act) {
        int4 s0 = *reinterpret_cast<const int4*>(src + gi);
        int4 s1 = *reinterpret_cast<const int4*>(src + gi + 4);
        int4 d0 = *reinterpret_cast<const int4*>(dst + gi);
        int4 d1 = *reinterpret_cast<const int4*>(dst + gi + 4);
        rec[0] = ((unsigned)d0.x << 14) | (unsigned)s0.x;
        rec[1] = ((unsigned)d0.y << 14) | (unsigned)s0.y;
        rec[2] = ((unsigned)d0.z << 14) | (unsigned)s0.z;
        rec[3] = ((unsigned)d0.w << 14) | (unsigned)s0.w;
        rec[4] = ((unsigned)d1.x << 14) | (unsigned)s1.x;
        rec[5] = ((unsigned)d1.y << 14) | (unsigned)s1.y;
        rec[6] = ((unsigned)d1.z << 14) | (unsigned)s1.z;
        rec[7] = ((unsigned)d1.w << 14) | (unsigned)s1.w;
        #pragma unroll
        for (int k = 0; k < 8; ++k) atomicAdd(&p.hist[rec[k] >> 19], 1);
    }
    __syncthreads();
    if (tid < 64) {          // wave-0 exclusive scan of hist
        int carry = 0;
        for (int c = 0; c < NB; c += 64) {
            int idx = c + tid;
            int v = (idx < NB) ? p.hist[idx] : 0;
            int incl = v;
            #pragma unroll
            for (int d = 1; d < 64; d <<= 1) {
                int t = __shfl_up(incl, d, 64);
                if (tid >= d) incl += t;
            }
            if (idx < NB) p.scanv[idx] = carry + incl - v;
            carry += __shfl(incl, 63, 64);
        }
        if (tid == 0) p.scanv[NB] = carry;
    }
    __syncthreads();
    for (int bb = tid; bb < NB; bb += 256) {
        p.gbase[bb] = atomicAdd(&bcur[bb], p.hist[bb]);
        p.lcur[bb]  = p.scanv[bb];
    }
    __syncthreads();
    if (act) {
        #pragma unroll
        for (int k = 0; k < 8; ++k) {
            int bb = rec[k] >> 19;
            int pp = atomicAdd(&p.lcur[bb], 1);
            p.stage[pp] = rec[k];
        }
    }
    __syncthreads();
    int tot = p.scanv[NB];
    for (int i = tid; i < tot; i += 256) {
        unsigned r = p.stage[i];
        int bb = r >> 19;
        edge_part[bb * RSTRIDE + p.gbase[bb] + (i - p.scanv[bb])] = r;
    }
}

// ---- build: one bucket -> offs/inv_sqrt + node-sorted CSR (ushort src) ----
__device__ __forceinline__ void build_block(const unsigned* __restrict__ edge_part,
                                            const int* __restrict__ bcur,
                                            int* __restrict__ offs,
                                            float* __restrict__ inv_sqrt,
                                            unsigned short* __restrict__ edge_src,
                                            SMbuild& b, int bid, int tid) {
    if (tid < 64) {
        int carry = 0;
        for (int c = 0; c < NB; c += 64) {
            int idx = c + tid;
            int v = (idx < NB) ? bcur[idx] : 0;
            int incl = v;
            #pragma unroll
            for (int d = 1; d < 64; d <<= 1) {
                int t = __shfl_up(incl, d, 64);
                if (tid >= d) incl += t;
            }
            if (idx < NB) b.sbase[idx] = carry + incl - v;
            carry += __shfl(incl, 63, 64);
        }
    }
    if (tid < 32) b.hist32[tid] = 0;
    __syncthreads();
    int cnt = bcur[bid];
    int base = b.sbase[bid];
    const unsigned* part = edge_part + (size_t)bid * RSTRIDE;
    for (int k = tid; k < cnt; k += 256)
        atomicAdd(&b.hist32[(part[k] >> 14) & 31], 1);
    __syncthreads();
    if (tid < 32) {
        int v = b.hist32[tid];
        int incl = v;
        #pragma unroll
        for (int d = 1; d < 32; d <<= 1) {
            int t = __shfl_up(incl, d, 32);
            if (tid >= d) incl += t;
        }
        int excl = incl - v;
        b.cur32[tid] = excl;
        int node = bid * 32 + tid;
        if (node < NN) {
            offs[node] = base + excl;
            inv_sqrt[node] = rsqrtf((float)(v + 1));
        }
        if (bid == NB - 1 && tid == 0) offs[NN] = base + cnt;
    }
    __syncthreads();
    for (int k = tid; k < cnt; k += 256) {
        unsigned r = part[k];
        int pp = atomicAdd(&b.cur32[(r >> 14) & 31], 1);
        b.stage[pp] = r & 0x3FFFu;
    }
    __syncthreads();
    for (int k = tid; k < cnt; k += 256)
        edge_src[base + k] = (unsigned short)b.stage[k];
}

// ======================= kernels =======================
__global__ __launch_bounds__(256) void part_gemm1_kernel(
        const int* __restrict__ src, const int* __restrict__ dst,
        int* __restrict__ bcur, unsigned* __restrict__ edge_part,
        const float* __restrict__ X, const float* __restrict__ W,
        unsigned short* __restrict__ Y) {
    __shared__ SMu sm;
    int tid = threadIdx.x;
    if (blockIdx.x >= NB) {
        gemm1_block(X, W, Y, sm.xs, blockIdx.x - NB, tid);
        return;
    }
    partition_block(src, dst, bcur, edge_part, sm.p, blockIdx.x, tid);
}

__global__ __launch_bounds__(256) void build_kernel(
        const unsigned* __restrict__ edge_part, const int* __restrict__ bcur,
        int* __restrict__ offs, float* __restrict__ inv_sqrt,
        unsigned short* __restrict__ edge_src) {
    __shared__ SMu sm;
    build_block(edge_part, bcur, offs, inv_sqrt, edge_src, sm.b,
                blockIdx.x, threadIdx.x);
}

// fused: aggregate 8 nodes (2 waves each, split chains) into LDS f32,
// then Y(bf16 packed) = relu-agg @ W.  NOUTc = output cols (128 or 64).
template<int NOUTc>
__global__ __launch_bounds__(1024) void agg_gemm_kernel(
        const unsigned short* __restrict__ H,      // [NN][128] bf16
        const unsigned short* __restrict__ esrc,
        const int* __restrict__ offs, const float* __restrict__ isqv,
        const float* __restrict__ bias, const float* __restrict__ W,
        unsigned* __restrict__ Yu) {               // [NN][NOUTc/2] packed u32
    __shared__ float As[8][128];
    __shared__ float2 red[8][64];
    int tid = threadIdx.x;
    int lane = tid & 63;
    int w = tid >> 6;               // 0..15
    int nl = w >> 1, sub = w & 1;
    int node = blockIdx.x * 8 + nl;
    int s = offs[node], e = offs[node + 1];
    int deg = e - s;
    int half = ((deg >> 1) + 3) & ~3;
    int js = s + sub * half;
    int mid = s + half;
    int je = sub ? e : (mid < e ? mid : e);
    int col = lane * 2;
    float2 acc = make_float2(0.f, 0.f);
    int j = js;
    for (; j + 4 <= je; j += 4) {
        int s0 = esrc[j], s1 = esrc[j + 1], s2 = esrc[j + 2], s3 = esrc[j + 3];
        float w0 = isqv[s0], w1 = isqv[s1], w2 = isqv[s2], w3 = isqv[s3];
        unsigned u0 = *reinterpret_cast<const unsigned*>(H + (size_t)s0 * 128 + col);
        unsigned u1 = *reinterpret_cast<const unsigned*>(H + (size_t)s1 * 128 + col);
        unsigned u2 = *reinterpret_cast<const unsigned*>(H + (size_t)s2 * 128 + col);
        unsigned u3 = *reinterpret_cast<const unsigned*>(H + (size_t)s3 * 128 + col);
        acc.x += w0 * bflo(u0); acc.y += w0 * bfhi(u0);
        acc.x += w1 * bflo(u1); acc.y += w1 * bfhi(u1);
        acc.x += w2 * bflo(u2); acc.y += w2 * bfhi(u2);
        acc.x += w3 * bflo(u3); acc.y += w3 * bfhi(u3);
    }
    for (; j < je; ++j) {
        int s0 = esrc[j];
        float w0 = isqv[s0];
        unsigned u0 = *reinterpret_cast<const unsigned*>(H + (size_t)s0 * 128 + col);
        acc.x += w0 * bflo(u0); acc.y += w0 * bfhi(u0);
    }
    if (sub) red[nl][lane] = acc;
    __syncthreads();
    if (!sub) {
        acc.x += red[nl][lane].x;
        acc.y += red[nl][lane].y;
        float isq = isqv[node];
        unsigned uv = *reinterpret_cast<const unsigned*>(H + (size_t)node * 128 + col);
        float self = isq * isq;
        As[nl][col]     = fmaxf(acc.x * isq + self * bflo(uv) + bias[col], 0.f);
        As[nl][col + 1] = fmaxf(acc.y * isq + self * bfhi(uv) + bias[col + 1], 0.f);
    }
    __syncthreads();
    // gemm: 8 rows x (NOUTc/2) packed cols; one thread per (row, col-pair)
    constexpr int PC = NOUTc / 2;
    if (tid < 8 * PC) {
        int r = tid / PC, pc = tid % PC, c = pc * 2;
        float2 a2 = make_float2(0.f, 0.f);
        #pragma unroll 8
        for (int k = 0; k < 128; ++k) {
            float xv = As[r][k];
            float2 wv2 = *reinterpret_cast<const float2*>(W + (size_t)k * NOUTc + c);
            a2.x += xv * wv2.x;
            a2.y += xv * wv2.y;
        }
        int gr = blockIdx.x * 8 + r;
        Yu[(size_t)gr * PC + pc] = (unsigned)f2bf(a2.x) | ((unsigned)f2bf(a2.y) << 16);
    }
}

// final 64-ch aggregation: 2 waves/node, f32 out, no relu
__global__ __launch_bounds__(128) void agg64_kernel(
        const unsigned short* __restrict__ H, const unsigned short* __restrict__ esrc,
        const int* __restrict__ offs, const float* __restrict__ inv_sqrt,
        const float* __restrict__ bias, float* __restrict__ out) {
    __shared__ float red[64];
    int node = blockIdx.x;
    int tid = threadIdx.x, lane = tid & 63, wv = tid >> 6;
    int s = offs[node], e = offs[node + 1];
    int deg = e - s;
    int half = ((deg >> 1) + 3) & ~3;
    int js = s + wv * half;
    int mid = s + half;
    int je = wv ? e : (mid < e ? mid : e);
    float acc = 0.f;
    int j = js;
    for (; j + 4 <= je; j += 4) {
        int s0 = esrc[j], s1 = esrc[j + 1], s2 = esrc[j + 2], s3 = esrc[j + 3];
        float w0 = inv_sqrt[s0], w1 = inv_sqrt[s1];
        float w2 = inv_sqrt[s2], w3 = inv_sqrt[s3];
        acc += w0 * bf1(H[(size_t)s0 * 64 + lane]);
        acc += w1 * bf1(H[(size_t)s1 * 64 + lane]);
        acc += w2 * bf1(H[(size_t)s2 * 64 + lane]);
        acc += w3 * bf1(H[(size_t)s3 * 64 + lane]);
    }
    for (; j < je; ++j) {
        int s0 = esrc[j];
        acc += inv_sqrt[s0] * bf1(H[(size_t)s0 * 64 + lane]);
    }
    if (wv) red[lane] = acc;
    __syncthreads();
    if (!wv) {
        acc += red[lane];
        float isq = inv_sqrt[node];
        float hv = bf1(H[(size_t)node * 64 + lane]);
        out[(size_t)node * 64 + lane] = acc * isq + isq * isq * hv + bias[lane];
    }
}

extern "C" void kernel_launch(void* const* d_in, const int* in_sizes, int n_in,
                              void* d_out, int out_size, void* d_ws, size_t ws_size,
                              hipStream_t stream) {
    const float* x  = (const float*)d_in[0];
    const int*   ei = (const int*)d_in[1];
    const float* W1 = (const float*)d_in[2];
    const float* b1 = (const float*)d_in[3];
    const float* W2 = (const float*)d_in[4];
    const float* b2 = (const float*)d_in[5];
    const float* W3 = (const float*)d_in[6];
    const float* b3 = (const float*)d_in[7];
    float* out = (float*)d_out;

    const int* src = ei;
    const int* dst = ei + NE;

    char* ws = (char*)d_ws;
    int*            bcur      = (int*)(ws);                        // 1,252 B
    float*          inv_sqrt  = (float*)(ws + 4096);               // 40,000 B
    int*            offs      = (int*)(ws + 45056);                // 40,004 B
    unsigned*       edge_part = (unsigned*)(ws + 86016);           // 3,365,376 B
    unsigned short* edge_src  = (unsigned short*)(ws + 3451392);   // 1,280,000 B
    unsigned short* T1        = (unsigned short*)(ws + 6011392);   // 2,560,000 B
    unsigned short* T2        = (unsigned short*)edge_part;        // alias (dead after build)
    unsigned short* T3        = T1;                                // alias (dead after agg_gemm2)

    zero_kernel<<<1, 320, 0, stream>>>(bcur);
    part_gemm1_kernel<<<NB + G1B, 256, 0, stream>>>(src, dst, bcur, edge_part,
                                                    x, W1, T1);
    build_kernel<<<NB, 256, 0, stream>>>(edge_part, bcur, offs, inv_sqrt, edge_src);
    agg_gemm_kernel<128><<<NN / 8, 1024, 0, stream>>>(T1, edge_src, offs, inv_sqrt,
                                                      b1, W2, (unsigned*)T2);
    agg_gemm_kernel<64><<<NN / 8, 1024, 0, stream>>>(T2, edge_src, offs, inv_sqrt,
                                                     b2, W3, (unsigned*)T3);
    agg64_kernel<<<NN, 128, 0, stream>>>(T3, edge_src, offs, inv_sqrt, b3, out);
}

// Round 11
// 133.156 us; speedup vs baseline: 1.2450x; 1.2450x over previous
//
#include <hip/hip_runtime.h>

#define NN 10000
#define NE 640000
#define NB 313          // buckets of 32 nodes; also # partition blocks
#define RSTRIDE 2688    // slots per bucket (mean 2045, sigma~45)
#define EPB 2048        // edges per partition block
#define G1B 1250        // gemm1 blocks (8 rows each)

__device__ __forceinline__ unsigned short f2bf(float x) {   // RNE
    unsigned u = __float_as_uint(x);
    u += 0x7FFFu + ((u >> 16) & 1u);
    return (unsigned short)(u >> 16);
}
__device__ __forceinline__ float bflo(unsigned u) { return __uint_as_float(u << 16); }
__device__ __forceinline__ float bfhi(unsigned u) { return __uint_as_float(u & 0xFFFF0000u); }

struct SMpart { int hist[NB]; int scanv[NB + 1]; int gbase[NB]; int lcur[NB];
                unsigned stage[EPB]; };
struct SMbuild { int sbase[NB + 1]; int hist32[32]; int cur32[32];
                 unsigned stage[RSTRIDE]; };
union SMu {
    SMpart p;
    SMbuild b;
    float xs[16][128];
};

__global__ void zero_kernel(int* __restrict__ cur) {
    if (threadIdx.x < NB) cur[threadIdx.x] = 0;
}

// ---- gemm1: 8 rows of Y = X[f32] @ W[128x128] -> bf16 ----
__device__ __forceinline__ void gemm1_block(const float* __restrict__ X,
                                            const float* __restrict__ W,
                                            unsigned short* __restrict__ Y,
                                            float (*xs)[128], int vb, int tid) {
    int row0 = vb * 8;
    for (int idx = tid; idx < 8 * 128; idx += 256) {
        int r = idx >> 7, k = idx & 127;
        xs[r][k] = X[(size_t)(row0 + r) * 128 + k];
    }
    __syncthreads();
    int ct = tid & 31, r = tid >> 5, c = ct * 4;
    float4 acc = make_float4(0.f, 0.f, 0.f, 0.f);
    #pragma unroll 8
    for (int k = 0; k < 128; ++k) {
        float xv = xs[r][k];
        float4 w = *reinterpret_cast<const float4*>(W + (size_t)k * 128 + c);
        acc.x += xv * w.x; acc.y += xv * w.y; acc.z += xv * w.z; acc.w += xv * w.w;
    }
    ushort4 o;
    o.x = f2bf(acc.x); o.y = f2bf(acc.y); o.z = f2bf(acc.z); o.w = f2bf(acc.w);
    *reinterpret_cast<ushort4*>(Y + (size_t)(row0 + r) * 128 + c) = o;
}

// ---- bf16-in GEMM: ROWS rows, NOUTc cols ----
template<int NOUTc, int ROWS>
__device__ __forceinline__ void gemm_bf_block(const unsigned short* __restrict__ Xb,
                                              const float* __restrict__ W,
                                              unsigned short* __restrict__ Y,
                                              float (*xs)[128], int vb, int tid) {
    int row0 = vb * ROWS;
    const unsigned* Xu = reinterpret_cast<const unsigned*>(Xb + (size_t)row0 * 128);
    for (int idx = tid; idx < ROWS * 64; idx += 256) {
        unsigned u = Xu[idx];
        int r = idx >> 6, kk = idx & 63;
        xs[r][kk * 2]     = bflo(u);
        xs[r][kk * 2 + 1] = bfhi(u);
    }
    __syncthreads();
    constexpr int COLT = NOUTc / 4;
    int ct = tid % COLT, r = tid / COLT, c = ct * 4;
    float4 acc = make_float4(0.f, 0.f, 0.f, 0.f);
    #pragma unroll 8
    for (int k = 0; k < 128; ++k) {
        float xv = xs[r][k];
        float4 w = *reinterpret_cast<const float4*>(W + (size_t)k * NOUTc + c);
        acc.x += xv * w.x; acc.y += xv * w.y; acc.z += xv * w.z; acc.w += xv * w.w;
    }
    ushort4 o;
    o.x = f2bf(acc.x); o.y = f2bf(acc.y); o.z = f2bf(acc.z); o.w = f2bf(acc.w);
    *reinterpret_cast<ushort4*>(Y + (size_t)(row0 + r) * NOUTc + c) = o;
}

// ---- partition: one block of EPB edges -> bucketed records ----
__device__ __forceinline__ void partition_block(const int* __restrict__ src,
                                                const int* __restrict__ dst,
                                                int* __restrict__ bcur,
                                                unsigned* __restrict__ edge_part,
                                                SMpart& p, int bid, int tid) {
    for (int i = tid; i < NB; i += 256) p.hist[i] = 0;
    __syncthreads();
    int gi = bid * EPB + tid * 8;
    unsigned rec[8];
    bool act = gi < NE;
    if (act) {
        int4 s0 = *reinterpret_cast<const int4*>(src + gi);
        int4 s1 = *reinterpret_cast<const int4*>(src + gi + 4);
        int4 d0 = *reinterpret_cast<const int4*>(dst + gi);
        int4 d1 = *reinterpret_cast<const int4*>(dst + gi + 4);
        rec[0] = ((unsigned)d0.x << 14) | (unsigned)s0.x;
        rec[1] = ((unsigned)d0.y << 14) | (unsigned)s0.y;
        rec[2] = ((unsigned)d0.z << 14) | (unsigned)s0.z;
        rec[3] = ((unsigned)d0.w << 14) | (unsigned)s0.w;
        rec[4] = ((unsigned)d1.x << 14) | (unsigned)s1.x;
        rec[5] = ((unsigned)d1.y << 14) | (unsigned)s1.y;
        rec[6] = ((unsigned)d1.z << 14) | (unsigned)s1.z;
        rec[7] = ((unsigned)d1.w << 14) | (unsigned)s1.w;
        #pragma unroll
        for (int k = 0; k < 8; ++k) atomicAdd(&p.hist[rec[k] >> 19], 1);
    }
    __syncthreads();
    if (tid < 64) {          // wave-0 exclusive scan of hist
        int carry = 0;
        for (int c = 0; c < NB; c += 64) {
            int idx = c + tid;
            int v = (idx < NB) ? p.hist[idx] : 0;
            int incl = v;
            #pragma unroll
            for (int d = 1; d < 64; d <<= 1) {
                int t = __shfl_up(incl, d, 64);
                if (tid >= d) incl += t;
            }
            if (idx < NB) p.scanv[idx] = carry + incl - v;
            carry += __shfl(incl, 63, 64);
        }
        if (tid == 0) p.scanv[NB] = carry;
    }
    __syncthreads();
    for (int bb = tid; bb < NB; bb += 256) {
        p.gbase[bb] = atomicAdd(&bcur[bb], p.hist[bb]);
        p.lcur[bb]  = p.scanv[bb];
    }
    __syncthreads();
    if (act) {
        #pragma unroll
        for (int k = 0; k < 8; ++k) {
            int bb = rec[k] >> 19;
            int pp = atomicAdd(&p.lcur[bb], 1);
            p.stage[pp] = rec[k];
        }
    }
    __syncthreads();
    int tot = p.scanv[NB];
    for (int i = tid; i < tot; i += 256) {
        unsigned r = p.stage[i];
        int bb = r >> 19;
        edge_part[bb * RSTRIDE + p.gbase[bb] + (i - p.scanv[bb])] = r;
    }
}

// ---- build: one bucket -> offs/inv_sqrt + node-sorted CSR (ushort src) ----
__device__ __forceinline__ void build_block(const unsigned* __restrict__ edge_part,
                                            const int* __restrict__ bcur,
                                            int* __restrict__ offs,
                                            float* __restrict__ inv_sqrt,
                                            unsigned short* __restrict__ edge_src,
                                            SMbuild& b, int bid, int tid) {
    if (tid < 64) {
        int carry = 0;
        for (int c = 0; c < NB; c += 64) {
            int idx = c + tid;
            int v = (idx < NB) ? bcur[idx] : 0;
            int incl = v;
            #pragma unroll
            for (int d = 1; d < 64; d <<= 1) {
                int t = __shfl_up(incl, d, 64);
                if (tid >= d) incl += t;
            }
            if (idx < NB) b.sbase[idx] = carry + incl - v;
            carry += __shfl(incl, 63, 64);
        }
    }
    if (tid < 32) b.hist32[tid] = 0;
    __syncthreads();
    int cnt = bcur[bid];
    int base = b.sbase[bid];
    const unsigned* part = edge_part + (size_t)bid * RSTRIDE;
    for (int k = tid; k < cnt; k += 256)
        atomicAdd(&b.hist32[(part[k] >> 14) & 31], 1);
    __syncthreads();
    if (tid < 32) {
        int v = b.hist32[tid];
        int incl = v;
        #pragma unroll
        for (int d = 1; d < 32; d <<= 1) {
            int t = __shfl_up(incl, d, 32);
            if (tid >= d) incl += t;
        }
        int excl = incl - v;
        b.cur32[tid] = excl;
        int node = bid * 32 + tid;
        if (node < NN) {
            offs[node] = base + excl;
            inv_sqrt[node] = rsqrtf((float)(v + 1));
        }
        if (bid == NB - 1 && tid == 0) offs[NN] = base + cnt;
    }
    __syncthreads();
    for (int k = tid; k < cnt; k += 256) {
        unsigned r = part[k];
        int pp = atomicAdd(&b.cur32[(r >> 14) & 31], 1);
        b.stage[pp] = r & 0x3FFFu;
    }
    __syncthreads();
    for (int k = tid; k < cnt; k += 256)
        edge_src[base + k] = (unsigned short)b.stage[k];
}

// ======================= kernels =======================
__global__ __launch_bounds__(256) void part_gemm1_kernel(
        const int* __restrict__ src, const int* __restrict__ dst,
        int* __restrict__ bcur, unsigned* __restrict__ edge_part,
        const float* __restrict__ X, const float* __restrict__ W,
        unsigned short* __restrict__ Y) {
    __shared__ SMu sm;
    int tid = threadIdx.x;
    if (blockIdx.x >= NB) {
        gemm1_block(X, W, Y, sm.xs, blockIdx.x - NB, tid);
        return;
    }
    partition_block(src, dst, bcur, edge_part, sm.p, blockIdx.x, tid);
}

__global__ __launch_bounds__(256) void build_kernel(
        const unsigned* __restrict__ edge_part, const int* __restrict__ bcur,
        int* __restrict__ offs, float* __restrict__ inv_sqrt,
        unsigned short* __restrict__ edge_src) {
    __shared__ SMu sm;
    build_block(edge_part, bcur, offs, inv_sqrt, edge_src, sm.b,
                blockIdx.x, threadIdx.x);
}

// 128-ch aggregation: 2 waves/node (split chains); within a wave, lanes 0-31
// process edge j (4 ch/lane), lanes 32-63 edge j+1. 8-edge unroll for MLP.
__global__ __launch_bounds__(128) void agg128_kernel(
        const unsigned short* __restrict__ H, const unsigned short* __restrict__ esrc,
        const int* __restrict__ offs, const float* __restrict__ isqv,
        const float* __restrict__ bias, unsigned* __restrict__ Aout) {
    __shared__ float4 red[32];
    int node = blockIdx.x;
    int tid = threadIdx.x, lane = tid & 63, wv = tid >> 6;
    int l = lane & 31, g = lane >> 5;
    int s = offs[node], e = offs[node + 1];
    int deg = e - s;
    int half = ((deg >> 1) + 7) & ~7;
    int js = s + wv * half;
    if (js > e) js = e;
    int mid = s + half;
    int je = wv ? e : (mid < e ? mid : e);
    int colb = l * 4;                   // 4 channels per lane
    float4 acc = make_float4(0.f, 0.f, 0.f, 0.f);
    int j = js;
    for (; j + 8 <= je; j += 8) {
        int sA = esrc[j + g],     sB = esrc[j + 2 + g];
        int sC = esrc[j + 4 + g], sD = esrc[j + 6 + g];
        float wA = isqv[sA], wB = isqv[sB], wC = isqv[sC], wD = isqv[sD];
        uint2 a = *reinterpret_cast<const uint2*>(H + (size_t)sA * 128 + colb);
        uint2 b = *reinterpret_cast<const uint2*>(H + (size_t)sB * 128 + colb);
        uint2 c = *reinterpret_cast<const uint2*>(H + (size_t)sC * 128 + colb);
        uint2 d = *reinterpret_cast<const uint2*>(H + (size_t)sD * 128 + colb);
        acc.x += wA * bflo(a.x); acc.y += wA * bfhi(a.x);
        acc.z += wA * bflo(a.y); acc.w += wA * bfhi(a.y);
        acc.x += wB * bflo(b.x); acc.y += wB * bfhi(b.x);
        acc.z += wB * bflo(b.y); acc.w += wB * bfhi(b.y);
        acc.x += wC * bflo(c.x); acc.y += wC * bfhi(c.x);
        acc.z += wC * bflo(c.y); acc.w += wC * bfhi(c.y);
        acc.x += wD * bflo(d.x); acc.y += wD * bfhi(d.x);
        acc.z += wD * bflo(d.y); acc.w += wD * bfhi(d.y);
    }
    for (; j + 2 <= je; j += 2) {
        int sA = esrc[j + g];
        float wA = isqv[sA];
        uint2 a = *reinterpret_cast<const uint2*>(H + (size_t)sA * 128 + colb);
        acc.x += wA * bflo(a.x); acc.y += wA * bfhi(a.x);
        acc.z += wA * bflo(a.y); acc.w += wA * bfhi(a.y);
    }
    if (j < je && g == 0) {            // single leftover edge (group 0 only)
        int sA = esrc[j];
        float wA = isqv[sA];
        uint2 a = *reinterpret_cast<const uint2*>(H + (size_t)sA * 128 + colb);
        acc.x += wA * bflo(a.x); acc.y += wA * bfhi(a.x);
        acc.z += wA * bflo(a.y); acc.w += wA * bfhi(a.y);
    }
    // fold group 1 (lanes 32-63) into group 0
    acc.x += __shfl_down(acc.x, 32);
    acc.y += __shfl_down(acc.y, 32);
    acc.z += __shfl_down(acc.z, 32);
    acc.w += __shfl_down(acc.w, 32);
    if (wv == 1 && lane < 32) red[lane] = acc;
    __syncthreads();
    if (wv == 0 && lane < 32) {
        float4 r = red[lane];
        acc.x += r.x; acc.y += r.y; acc.z += r.z; acc.w += r.w;
        float isq = isqv[node];
        uint2 uv = *reinterpret_cast<const uint2*>(H + (size_t)node * 128 + colb);
        float self = isq * isq;
        float o0 = fmaxf(acc.x * isq + self * bflo(uv.x) + bias[colb],     0.f);
        float o1 = fmaxf(acc.y * isq + self * bfhi(uv.x) + bias[colb + 1], 0.f);
        float o2 = fmaxf(acc.z * isq + self * bflo(uv.y) + bias[colb + 2], 0.f);
        float o3 = fmaxf(acc.w * isq + self * bfhi(uv.y) + bias[colb + 3], 0.f);
        uint2 ov;
        ov.x = (unsigned)f2bf(o0) | ((unsigned)f2bf(o1) << 16);
        ov.y = (unsigned)f2bf(o2) | ((unsigned)f2bf(o3) << 16);
        *reinterpret_cast<uint2*>(Aout + (size_t)node * 64 + l * 2) = ov;
    }
}

// 64-ch final aggregation: same structure, 2 ch/lane, f32 out, no relu
__global__ __launch_bounds__(128) void agg64_kernel(
        const unsigned short* __restrict__ H, const unsigned short* __restrict__ esrc,
        const int* __restrict__ offs, const float* __restrict__ isqv,
        const float* __restrict__ bias, float* __restrict__ out) {
    __shared__ float2 red[32];
    int node = blockIdx.x;
    int tid = threadIdx.x, lane = tid & 63, wv = tid >> 6;
    int l = lane & 31, g = lane >> 5;
    int s = offs[node], e = offs[node + 1];
    int deg = e - s;
    int half = ((deg >> 1) + 7) & ~7;
    int js = s + wv * half;
    if (js > e) js = e;
    int mid = s + half;
    int je = wv ? e : (mid < e ? mid : e);
    int colb = l * 2;                   // 2 channels per lane
    float2 acc = make_float2(0.f, 0.f);
    int j = js;
    for (; j + 8 <= je; j += 8) {
        int sA = esrc[j + g],     sB = esrc[j + 2 + g];
        int sC = esrc[j + 4 + g], sD = esrc[j + 6 + g];
        float wA = isqv[sA], wB = isqv[sB], wC = isqv[sC], wD = isqv[sD];
        unsigned a = *reinterpret_cast<const unsigned*>(H + (size_t)sA * 64 + colb);
        unsigned b = *reinterpret_cast<const unsigned*>(H + (size_t)sB * 64 + colb);
        unsigned c = *reinterpret_cast<const unsigned*>(H + (size_t)sC * 64 + colb);
        unsigned d = *reinterpret_cast<const unsigned*>(H + (size_t)sD * 64 + colb);
        acc.x += wA * bflo(a); acc.y += wA * bfhi(a);
        acc.x += wB * bflo(b); acc.y += wB * bfhi(b);
        acc.x += wC * bflo(c); acc.y += wC * bfhi(c);
        acc.x += wD * bflo(d); acc.y += wD * bfhi(d);
    }
    for (; j + 2 <= je; j += 2) {
        int sA = esrc[j + g];
        float wA = isqv[sA];
        unsigned a = *reinterpret_cast<const unsigned*>(H + (size_t)sA * 64 + colb);
        acc.x += wA * bflo(a); acc.y += wA * bfhi(a);
    }
    if (j < je && g == 0) {
        int sA = esrc[j];
        float wA = isqv[sA];
        unsigned a = *reinterpret_cast<const unsigned*>(H + (size_t)sA * 64 + colb);
        acc.x += wA * bflo(a); acc.y += wA * bfhi(a);
    }
    acc.x += __shfl_down(acc.x, 32);
    acc.y += __shfl_down(acc.y, 32);
    if (wv == 1 && lane < 32) red[lane] = acc;
    __syncthreads();
    if (wv == 0 && lane < 32) {
        float2 r = red[lane];
        acc.x += r.x; acc.y += r.y;
        float isq = isqv[node];
        unsigned uv = *reinterpret_cast<const unsigned*>(H + (size_t)node * 64 + colb);
        float self = isq * isq;
        float2 ov;
        ov.x = acc.x * isq + self * bflo(uv) + bias[colb];
        ov.y = acc.y * isq + self * bfhi(uv) + bias[colb + 1];
        *reinterpret_cast<float2*>(out + (size_t)node * 64 + colb) = ov;
    }
}

template<int N>
__global__ __launch_bounds__(256) void gemm_bf_kernel(
        const unsigned short* __restrict__ X, const float* __restrict__ W,
        unsigned short* __restrict__ Y) {
    __shared__ SMu sm;
    gemm_bf_block<N, 256 / (N / 4)>(X, W, Y, sm.xs, blockIdx.x, threadIdx.x);
}

extern "C" void kernel_launch(void* const* d_in, const int* in_sizes, int n_in,
                              void* d_out, int out_size, void* d_ws, size_t ws_size,
                              hipStream_t stream) {
    const float* x  = (const float*)d_in[0];
    const int*   ei = (const int*)d_in[1];
    const float* W1 = (const float*)d_in[2];
    const float* b1 = (const float*)d_in[3];
    const float* W2 = (const float*)d_in[4];
    const float* b2 = (const float*)d_in[5];
    const float* W3 = (const float*)d_in[6];
    const float* b3 = (const float*)d_in[7];
    float* out = (float*)d_out;

    const int* src = ei;
    const int* dst = ei + NE;

    char* ws = (char*)d_ws;
    int*            bcur      = (int*)(ws);                        // 1,252 B
    float*          inv_sqrt  = (float*)(ws + 4096);               // 40,000 B
    int*            offs      = (int*)(ws + 45056);                // 40,004 B
    unsigned*       edge_part = (unsigned*)(ws + 86016);           // 3,365,376 B
    unsigned short* edge_src  = (unsigned short*)(ws + 3451392);   // 1,280,000 B
    unsigned short* T1        = (unsigned short*)(ws + 6011392);   // 2,560,000 B
    unsigned short* A         = (unsigned short*)(ws + 8571392);   // 2,560,000 B
    unsigned short* T2        = (unsigned short*)edge_part;        // alias (dead after build)
    unsigned short* T3        = T1;                                // alias (dead after agg1)

    zero_kernel<<<1, 320, 0, stream>>>(bcur);
    part_gemm1_kernel<<<NB + G1B, 256, 0, stream>>>(src, dst, bcur, edge_part,
                                                    x, W1, T1);
    build_kernel<<<NB, 256, 0, stream>>>(edge_part, bcur, offs, inv_sqrt, edge_src);
    agg128_kernel<<<NN, 128, 0, stream>>>(T1, edge_src, offs, inv_sqrt, b1,
                                          (unsigned*)A);
    gemm_bf_kernel<128><<<NN / 8, 256, 0, stream>>>(A, W2, T2);
    agg128_kernel<<<NN, 128, 0, stream>>>(T2, edge_src, offs, inv_sqrt, b2,
                                          (unsigned*)A);
    gemm_bf_kernel<64><<<NN / 16, 256, 0, stream>>>(A, W3, T3);
    agg64_kernel<<<NN, 128, 0, stream>>>(T3, edge_src, offs, inv_sqrt, b3, out);
}

// Round 12
// 121.382 us; speedup vs baseline: 1.3658x; 1.0970x over previous
//
#include <hip/hip_runtime.h>

#define NN 10000
#define NE 640000
#define NB 313          // buckets of 32 nodes; also # partition blocks
#define RSTRIDE 2688    // slots per bucket (mean 2045, sigma~45)
#define EPB 2048        // edges per partition block
#define G1B 1250        // gemm1 blocks (8 rows each)

__device__ __forceinline__ unsigned short f2bf(float x) {   // RNE
    unsigned u = __float_as_uint(x);
    u += 0x7FFFu + ((u >> 16) & 1u);
    return (unsigned short)(u >> 16);
}
__device__ __forceinline__ float bflo(unsigned u) { return __uint_as_float(u << 16); }
__device__ __forceinline__ float bfhi(unsigned u) { return __uint_as_float(u & 0xFFFF0000u); }

__device__ __forceinline__ void acc8w(float* acc, uint4 u, float w) {
    acc[0] += w * bflo(u.x); acc[1] += w * bfhi(u.x);
    acc[2] += w * bflo(u.y); acc[3] += w * bfhi(u.y);
    acc[4] += w * bflo(u.z); acc[5] += w * bfhi(u.z);
    acc[6] += w * bflo(u.w); acc[7] += w * bfhi(u.w);
}
__device__ __forceinline__ void acc8p(float* acc, uint4 u) {
    acc[0] += bflo(u.x); acc[1] += bfhi(u.x);
    acc[2] += bflo(u.y); acc[3] += bfhi(u.y);
    acc[4] += bflo(u.z); acc[5] += bfhi(u.z);
    acc[6] += bflo(u.w); acc[7] += bfhi(u.w);
}
__device__ __forceinline__ void acc4p(float* acc, uint2 u) {
    acc[0] += bflo(u.x); acc[1] += bfhi(u.x);
    acc[2] += bflo(u.y); acc[3] += bfhi(u.y);
}

struct SMpart { int hist[NB]; int scanv[NB + 1]; int gbase[NB]; int lcur[NB];
                unsigned stage[EPB]; };
struct SMbuild { int sbase[NB + 1]; int hist32[32]; int cur32[32];
                 unsigned stage[RSTRIDE]; };
union SMu {
    SMpart p;
    SMbuild b;
    float xs[16][128];
};

__global__ void zero_kernel(int* __restrict__ cur) {
    if (threadIdx.x < NB) cur[threadIdx.x] = 0;
}

// ---- gemm1: 8 rows of Y = X[f32] @ W[128x128] -> bf16 (unscaled) ----
__device__ __forceinline__ void gemm1_block(const float* __restrict__ X,
                                            const float* __restrict__ W,
                                            unsigned short* __restrict__ Y,
                                            float (*xs)[128], int vb, int tid) {
    int row0 = vb * 8;
    for (int idx = tid; idx < 8 * 128; idx += 256) {
        int r = idx >> 7, k = idx & 127;
        xs[r][k] = X[(size_t)(row0 + r) * 128 + k];
    }
    __syncthreads();
    int ct = tid & 31, r = tid >> 5, c = ct * 4;
    float4 acc = make_float4(0.f, 0.f, 0.f, 0.f);
    #pragma unroll 8
    for (int k = 0; k < 128; ++k) {
        float xv = xs[r][k];
        float4 w = *reinterpret_cast<const float4*>(W + (size_t)k * 128 + c);
        acc.x += xv * w.x; acc.y += xv * w.y; acc.z += xv * w.z; acc.w += xv * w.w;
    }
    ushort4 o;
    o.x = f2bf(acc.x); o.y = f2bf(acc.y); o.z = f2bf(acc.z); o.w = f2bf(acc.w);
    *reinterpret_cast<ushort4*>(Y + (size_t)(row0 + r) * 128 + c) = o;
}

// ---- bf16-in GEMM; optional per-row isq prescale in epilogue (f32) ----
template<int NOUTc, int ROWS, bool SCALE>
__device__ __forceinline__ void gemm_bf_block(const unsigned short* __restrict__ Xb,
                                              const float* __restrict__ W,
                                              const float* __restrict__ isqv,
                                              unsigned short* __restrict__ Y,
                                              float (*xs)[128], int vb, int tid) {
    int row0 = vb * ROWS;
    const unsigned* Xu = reinterpret_cast<const unsigned*>(Xb + (size_t)row0 * 128);
    for (int idx = tid; idx < ROWS * 64; idx += 256) {
        unsigned u = Xu[idx];
        int r = idx >> 6, kk = idx & 63;
        xs[r][kk * 2]     = bflo(u);
        xs[r][kk * 2 + 1] = bfhi(u);
    }
    __syncthreads();
    constexpr int COLT = NOUTc / 4;
    int ct = tid % COLT, r = tid / COLT, c = ct * 4;
    float4 acc = make_float4(0.f, 0.f, 0.f, 0.f);
    #pragma unroll 8
    for (int k = 0; k < 128; ++k) {
        float xv = xs[r][k];
        float4 w = *reinterpret_cast<const float4*>(W + (size_t)k * NOUTc + c);
        acc.x += xv * w.x; acc.y += xv * w.y; acc.z += xv * w.z; acc.w += xv * w.w;
    }
    int gr = row0 + r;
    if (SCALE) {
        float sc = isqv[gr];
        acc.x *= sc; acc.y *= sc; acc.z *= sc; acc.w *= sc;
    }
    ushort4 o;
    o.x = f2bf(acc.x); o.y = f2bf(acc.y); o.z = f2bf(acc.z); o.w = f2bf(acc.w);
    *reinterpret_cast<ushort4*>(Y + (size_t)gr * NOUTc + c) = o;
}

// ---- partition: one block of EPB edges -> bucketed records ----
__device__ __forceinline__ void partition_block(const int* __restrict__ src,
                                                const int* __restrict__ dst,
                                                int* __restrict__ bcur,
                                                unsigned* __restrict__ edge_part,
                                                SMpart& p, int bid, int tid) {
    for (int i = tid; i < NB; i += 256) p.hist[i] = 0;
    __syncthreads();
    int gi = bid * EPB + tid * 8;
    unsigned rec[8];
    bool act = gi < NE;
    if (act) {
        int4 s0 = *reinterpret_cast<const int4*>(src + gi);
        int4 s1 = *reinterpret_cast<const int4*>(src + gi + 4);
        int4 d0 = *reinterpret_cast<const int4*>(dst + gi);
        int4 d1 = *reinterpret_cast<const int4*>(dst + gi + 4);
        rec[0] = ((unsigned)d0.x << 14) | (unsigned)s0.x;
        rec[1] = ((unsigned)d0.y << 14) | (unsigned)s0.y;
        rec[2] = ((unsigned)d0.z << 14) | (unsigned)s0.z;
        rec[3] = ((unsigned)d0.w << 14) | (unsigned)s0.w;
        rec[4] = ((unsigned)d1.x << 14) | (unsigned)s1.x;
        rec[5] = ((unsigned)d1.y << 14) | (unsigned)s1.y;
        rec[6] = ((unsigned)d1.z << 14) | (unsigned)s1.z;
        rec[7] = ((unsigned)d1.w << 14) | (unsigned)s1.w;
        #pragma unroll
        for (int k = 0; k < 8; ++k) atomicAdd(&p.hist[rec[k] >> 19], 1);
    }
    __syncthreads();
    if (tid < 64) {          // wave-0 exclusive scan of hist
        int carry = 0;
        for (int c = 0; c < NB; c += 64) {
            int idx = c + tid;
            int v = (idx < NB) ? p.hist[idx] : 0;
            int incl = v;
            #pragma unroll
            for (int d = 1; d < 64; d <<= 1) {
                int t = __shfl_up(incl, d, 64);
                if (tid >= d) incl += t;
            }
            if (idx < NB) p.scanv[idx] = carry + incl - v;
            carry += __shfl(incl, 63, 64);
        }
        if (tid == 0) p.scanv[NB] = carry;
    }
    __syncthreads();
    for (int bb = tid; bb < NB; bb += 256) {
        p.gbase[bb] = atomicAdd(&bcur[bb], p.hist[bb]);
        p.lcur[bb]  = p.scanv[bb];
    }
    __syncthreads();
    if (act) {
        #pragma unroll
        for (int k = 0; k < 8; ++k) {
            int bb = rec[k] >> 19;
            int pp = atomicAdd(&p.lcur[bb], 1);
            p.stage[pp] = rec[k];
        }
    }
    __syncthreads();
    int tot = p.scanv[NB];
    for (int i = tid; i < tot; i += 256) {
        unsigned r = p.stage[i];
        int bb = r >> 19;
        edge_part[bb * RSTRIDE + p.gbase[bb] + (i - p.scanv[bb])] = r;
    }
}

// ---- build: one bucket -> offs/inv_sqrt + node-sorted CSR (ushort src) ----
__device__ __forceinline__ void build_block(const unsigned* __restrict__ edge_part,
                                            const int* __restrict__ bcur,
                                            int* __restrict__ offs,
                                            float* __restrict__ inv_sqrt,
                                            unsigned short* __restrict__ edge_src,
                                            SMbuild& b, int bid, int tid) {
    if (tid < 64) {
        int carry = 0;
        for (int c = 0; c < NB; c += 64) {
            int idx = c + tid;
            int v = (idx < NB) ? bcur[idx] : 0;
            int incl = v;
            #pragma unroll
            for (int d = 1; d < 64; d <<= 1) {
                int t = __shfl_up(incl, d, 64);
                if (tid >= d) incl += t;
            }
            if (idx < NB) b.sbase[idx] = carry + incl - v;
            carry += __shfl(incl, 63, 64);
        }
    }
    if (tid < 32) b.hist32[tid] = 0;
    __syncthreads();
    int cnt = bcur[bid];
    int base = b.sbase[bid];
    const unsigned* part = edge_part + (size_t)bid * RSTRIDE;
    for (int k = tid; k < cnt; k += 256)
        atomicAdd(&b.hist32[(part[k] >> 14) & 31], 1);
    __syncthreads();
    if (tid < 32) {
        int v = b.hist32[tid];
        int incl = v;
        #pragma unroll
        for (int d = 1; d < 32; d <<= 1) {
            int t = __shfl_up(incl, d, 32);
            if (tid >= d) incl += t;
        }
        int excl = incl - v;
        b.cur32[tid] = excl;
        int node = bid * 32 + tid;
        if (node < NN) {
            offs[node] = base + excl;
            inv_sqrt[node] = rsqrtf((float)(v + 1));
        }
        if (bid == NB - 1 && tid == 0) offs[NN] = base + cnt;
    }
    __syncthreads();
    for (int k = tid; k < cnt; k += 256) {
        unsigned r = part[k];
        int pp = atomicAdd(&b.cur32[(r >> 14) & 31], 1);
        b.stage[pp] = r & 0x3FFFu;
    }
    __syncthreads();
    for (int k = tid; k < cnt; k += 256)
        edge_src[base + k] = (unsigned short)b.stage[k];
}

// ======================= kernels =======================
__global__ __launch_bounds__(256) void part_gemm1_kernel(
        const int* __restrict__ src, const int* __restrict__ dst,
        int* __restrict__ bcur, unsigned* __restrict__ edge_part,
        const float* __restrict__ X, const float* __restrict__ W,
        unsigned short* __restrict__ Y) {
    __shared__ SMu sm;
    int tid = threadIdx.x;
    if (blockIdx.x >= NB) {
        gemm1_block(X, W, Y, sm.xs, blockIdx.x - NB, tid);
        return;
    }
    partition_block(src, dst, bcur, edge_part, sm.p, blockIdx.x, tid);
}

__global__ __launch_bounds__(256) void build_kernel(
        const unsigned* __restrict__ edge_part, const int* __restrict__ bcur,
        int* __restrict__ offs, float* __restrict__ inv_sqrt,
        unsigned short* __restrict__ edge_src) {
    __shared__ SMu sm;
    build_block(edge_part, bcur, offs, inv_sqrt, edge_src, sm.b,
                blockIdx.x, threadIdx.x);
}

// 128-ch aggregation. 2 waves/node (split chains); 4 groups of 16 lanes per
// wave, each group one edge (uint4 = 8 ch/lane); 16-edge unroll (4 gathers
// in flight/lane). PS: H rows pre-scaled by isq_src (no weight gather).
template<bool PS>
__global__ __launch_bounds__(128) void agg128_kernel(
        const unsigned short* __restrict__ H, const unsigned short* __restrict__ esrc,
        const int* __restrict__ offs, const float* __restrict__ isqv,
        const float* __restrict__ bias, uint4* __restrict__ Aout) {
    __shared__ float red[16][9];
    int node = blockIdx.x;
    int tid = threadIdx.x, lane = tid & 63, wv = tid >> 6;
    int l = lane & 15, g = lane >> 4;
    int s = offs[node], e = offs[node + 1];
    int deg = e - s;
    int half = ((deg >> 1) + 3) & ~3;
    int js = s + wv * half;
    if (js > e) js = e;
    int mid = s + half;
    int je = wv ? e : (mid < e ? mid : e);
    int colb = l * 8;
    float acc[8];
    #pragma unroll
    for (int i = 0; i < 8; ++i) acc[i] = 0.f;
    int j = js;
    for (; j + 16 <= je; j += 16) {
        int sA = esrc[j + g],      sB = esrc[j + 4 + g];
        int sC = esrc[j + 8 + g],  sD = esrc[j + 12 + g];
        uint4 a = *reinterpret_cast<const uint4*>(H + (size_t)sA * 128 + colb);
        uint4 b = *reinterpret_cast<const uint4*>(H + (size_t)sB * 128 + colb);
        uint4 c = *reinterpret_cast<const uint4*>(H + (size_t)sC * 128 + colb);
        uint4 d = *reinterpret_cast<const uint4*>(H + (size_t)sD * 128 + colb);
        if (PS) {
            acc8p(acc, a); acc8p(acc, b); acc8p(acc, c); acc8p(acc, d);
        } else {
            float wA = isqv[sA], wB = isqv[sB], wC = isqv[sC], wD = isqv[sD];
            acc8w(acc, a, wA); acc8w(acc, b, wB);
            acc8w(acc, c, wC); acc8w(acc, d, wD);
        }
    }
    for (; j + 4 <= je; j += 4) {
        int sA = esrc[j + g];
        uint4 a = *reinterpret_cast<const uint4*>(H + (size_t)sA * 128 + colb);
        if (PS) { acc8p(acc, a); }
        else    { acc8w(acc, a, isqv[sA]); }
    }
    int rem = je - j;
    if (g < rem) {
        int sA = esrc[j + g];
        uint4 a = *reinterpret_cast<const uint4*>(H + (size_t)sA * 128 + colb);
        if (PS) { acc8p(acc, a); }
        else    { acc8w(acc, a, isqv[sA]); }
    }
    #pragma unroll
    for (int i = 0; i < 8; ++i) {
        acc[i] += __shfl_down(acc[i], 32);
        acc[i] += __shfl_down(acc[i], 16);
    }
    if (wv == 1 && lane < 16) {
        #pragma unroll
        for (int i = 0; i < 8; ++i) red[l][i] = acc[i];
    }
    __syncthreads();
    if (wv == 0 && lane < 16) {
        float isq = isqv[node];
        uint4 uv = *reinterpret_cast<const uint4*>(H + (size_t)node * 128 + colb);
        float sv[8] = { bflo(uv.x), bfhi(uv.x), bflo(uv.y), bfhi(uv.y),
                        bflo(uv.z), bfhi(uv.z), bflo(uv.w), bfhi(uv.w) };
        float o[8];
        #pragma unroll
        for (int i = 0; i < 8; ++i) {
            float a = acc[i] + red[l][i];
            a += PS ? sv[i] : isq * sv[i];
            o[i] = fmaxf(isq * a + bias[colb + i], 0.f);
        }
        uint4 ov;
        ov.x = (unsigned)f2bf(o[0]) | ((unsigned)f2bf(o[1]) << 16);
        ov.y = (unsigned)f2bf(o[2]) | ((unsigned)f2bf(o[3]) << 16);
        ov.z = (unsigned)f2bf(o[4]) | ((unsigned)f2bf(o[5]) << 16);
        ov.w = (unsigned)f2bf(o[6]) | ((unsigned)f2bf(o[7]) << 16);
        Aout[(size_t)node * 16 + l] = ov;
    }
}

// 64-ch final aggregation (prescaled H), f32 out, no relu
__global__ __launch_bounds__(128) void agg64_kernel(
        const unsigned short* __restrict__ H, const unsigned short* __restrict__ esrc,
        const int* __restrict__ offs, const float* __restrict__ isqv,
        const float* __restrict__ bias, float* __restrict__ out) {
    __shared__ float red[16][5];
    int node = blockIdx.x;
    int tid = threadIdx.x, lane = tid & 63, wv = tid >> 6;
    int l = lane & 15, g = lane >> 4;
    int s = offs[node], e = offs[node + 1];
    int deg = e - s;
    int half = ((deg >> 1) + 3) & ~3;
    int js = s + wv * half;
    if (js > e) js = e;
    int mid = s + half;
    int je = wv ? e : (mid < e ? mid : e);
    int colb = l * 4;
    float acc[4] = {0.f, 0.f, 0.f, 0.f};
    int j = js;
    for (; j + 16 <= je; j += 16) {
        int sA = esrc[j + g],      sB = esrc[j + 4 + g];
        int sC = esrc[j + 8 + g],  sD = esrc[j + 12 + g];
        uint2 a = *reinterpret_cast<const uint2*>(H + (size_t)sA * 64 + colb);
        uint2 b = *reinterpret_cast<const uint2*>(H + (size_t)sB * 64 + colb);
        uint2 c = *reinterpret_cast<const uint2*>(H + (size_t)sC * 64 + colb);
        uint2 d = *reinterpret_cast<const uint2*>(H + (size_t)sD * 64 + colb);
        acc4p(acc, a); acc4p(acc, b); acc4p(acc, c); acc4p(acc, d);
    }
    for (; j + 4 <= je; j += 4) {
        int sA = esrc[j + g];
        uint2 a = *reinterpret_cast<const uint2*>(H + (size_t)sA * 64 + colb);
        acc4p(acc, a);
    }
    int rem = je - j;
    if (g < rem) {
        int sA = esrc[j + g];
        uint2 a = *reinterpret_cast<const uint2*>(H + (size_t)sA * 64 + colb);
        acc4p(acc, a);
    }
    #pragma unroll
    for (int i = 0; i < 4; ++i) {
        acc[i] += __shfl_down(acc[i], 32);
        acc[i] += __shfl_down(acc[i], 16);
    }
    if (wv == 1 && lane < 16) {
        #pragma unroll
        for (int i = 0; i < 4; ++i) red[l][i] = acc[i];
    }
    __syncthreads();
    if (wv == 0 && lane < 16) {
        float isq = isqv[node];
        uint2 uv = *reinterpret_cast<const uint2*>(H + (size_t)node * 64 + colb);
        float sv[4] = { bflo(uv.x), bfhi(uv.x), bflo(uv.y), bfhi(uv.y) };
        float4 ov;
        float o[4];
        #pragma unroll
        for (int i = 0; i < 4; ++i)
            o[i] = isq * (acc[i] + red[l][i] + sv[i]) + bias[colb + i];
        ov.x = o[0]; ov.y = o[1]; ov.z = o[2]; ov.w = o[3];
        *reinterpret_cast<float4*>(out + (size_t)node * 64 + colb) = ov;
    }
}

template<int N, bool SCALE>
__global__ __launch_bounds__(256) void gemm_bf_kernel(
        const unsigned short* __restrict__ X, const float* __restrict__ W,
        const float* __restrict__ isqv, unsigned short* __restrict__ Y) {
    __shared__ SMu sm;
    gemm_bf_block<N, 256 / (N / 4), SCALE>(X, W, isqv, Y, sm.xs,
                                           blockIdx.x, threadIdx.x);
}

extern "C" void kernel_launch(void* const* d_in, const int* in_sizes, int n_in,
                              void* d_out, int out_size, void* d_ws, size_t ws_size,
                              hipStream_t stream) {
    const float* x  = (const float*)d_in[0];
    const int*   ei = (const int*)d_in[1];
    const float* W1 = (const float*)d_in[2];
    const float* b1 = (const float*)d_in[3];
    const float* W2 = (const float*)d_in[4];
    const float* b2 = (const float*)d_in[5];
    const float* W3 = (const float*)d_in[6];
    const float* b3 = (const float*)d_in[7];
    float* out = (float*)d_out;

    const int* src = ei;
    const int* dst = ei + NE;

    char* ws = (char*)d_ws;
    int*            bcur      = (int*)(ws);                        // 1,252 B
    float*          inv_sqrt  = (float*)(ws + 4096);               // 40,000 B
    int*            offs      = (int*)(ws + 45056);                // 40,004 B
    unsigned*       edge_part = (unsigned*)(ws + 86016);           // 3,365,376 B
    unsigned short* edge_src  = (unsigned short*)(ws + 3451392);   // 1,280,000 B
    unsigned short* T1        = (unsigned short*)(ws + 6011392);   // 2,560,000 B
    unsigned short* A         = (unsigned short*)(ws + 8571392);   // 2,560,000 B
    unsigned short* T2        = (unsigned short*)edge_part;        // alias (dead after build)
    unsigned short* T3        = T1;                                // alias (dead after agg1)

    zero_kernel<<<1, 320, 0, stream>>>(bcur);
    part_gemm1_kernel<<<NB + G1B, 256, 0, stream>>>(src, dst, bcur, edge_part,
                                                    x, W1, T1);
    build_kernel<<<NB, 256, 0, stream>>>(edge_part, bcur, offs, inv_sqrt, edge_src);
    agg128_kernel<false><<<NN, 128, 0, stream>>>(T1, edge_src, offs, inv_sqrt, b1,
                                                 (uint4*)A);
    gemm_bf_kernel<128, true><<<NN / 8, 256, 0, stream>>>(A, W2, inv_sqrt, T2);
    agg128_kernel<true><<<NN, 128, 0, stream>>>(T2, edge_src, offs, inv_sqrt, b2,
                                                (uint4*)A);
    gemm_bf_kernel<64, true><<<NN / 16, 256, 0, stream>>>(A, W3, inv_sqrt, T3);
    agg64_kernel<<<NN, 128, 0, stream>>>(T3, edge_src, offs, inv_sqrt, b3, out);
}